// Round 4
// baseline (241.779 us; speedup 1.0000x reference)
//
#include <hip/hip_runtime.h>

#define HW 16384
#define C 128

typedef __attribute__((ext_vector_type(8))) short short8;
typedef __attribute__((ext_vector_type(4))) float f32x4;

__device__ __forceinline__ unsigned short f2bf(float f) {
  union { float f; unsigned u; } v; v.f = f;
  return (unsigned short)((v.u + 0x7fffu + ((v.u >> 16) & 1u)) >> 16);
}
__device__ __forceinline__ float bflo(unsigned w) {  // low bf16 -> f32 (1 op)
  union { unsigned u; float f; } v; v.u = w << 16; return v.f;
}
__device__ __forceinline__ float bfhi(unsigned w) {  // high bf16 -> f32 (1 op)
  union { unsigned u; float f; } v; v.u = w & 0xffff0000u; return v.f;
}
__device__ __forceinline__ unsigned long long pk4(float a, float b, float c, float d) {
  return (unsigned long long)f2bf(a) | ((unsigned long long)f2bf(b) << 16) |
         ((unsigned long long)f2bf(c) << 32) | ((unsigned long long)f2bf(d) << 48);
}

// ---------------- Kernel 1: qkv = w_qkv @ x  (bf16 MFMA) ----------------------
__global__ __launch_bounds__(256) void k_qkv(const float* __restrict__ x,
                                             const float* __restrict__ w_qkv,
                                             unsigned short* __restrict__ qb,
                                             unsigned short* __restrict__ kb,
                                             unsigned short* __restrict__ vb) {
  __shared__ __align__(16) unsigned short Xs[128 * 128];  // [pix][k] xor-swizzled
  __shared__ __align__(16) unsigned short Ws[128 * 128];  // [och][k] xor-swizzled
  const int t = threadIdx.x;
  const int gpix0 = blockIdx.x * 128;
  const int b = gpix0 >> 14;
  const int hw0 = gpix0 & (HW - 1);
  const int och0 = blockIdx.y * 128;

  const float* xb = x + (size_t)b * C * HW + hw0;
  #pragma unroll
  for (int i = 0; i < 16; ++i) {
    int linear = i * 256 + t;
    int p = linear & 127;
    int c4 = (linear >> 7) * 4;
    float a0 = xb[(size_t)(c4 + 0) * HW + p];
    float a1 = xb[(size_t)(c4 + 1) * HW + p];
    float a2 = xb[(size_t)(c4 + 2) * HW + p];
    float a3 = xb[(size_t)(c4 + 3) * HW + p];
    int cc = c4 ^ ((p & 7) << 3);
    *(unsigned long long*)&Xs[p * 128 + cc] = pk4(a0, a1, a2, a3);
  }
  const float* wb = w_qkv + (size_t)och0 * C;
  #pragma unroll
  for (int i = 0; i < 16; ++i) {
    int linear = i * 256 + t;
    int c4 = (linear & 31) * 4;
    int o = linear >> 5;
    float4 w4 = *(const float4*)(wb + (size_t)o * C + c4);
    int cc = c4 ^ ((o & 7) << 3);
    *(unsigned long long*)&Ws[o * 128 + cc] = pk4(w4.x, w4.y, w4.z, w4.w);
  }
  __syncthreads();

  const int wave = t >> 6, lane = t & 63;
  const int wr = wave >> 1, wc = wave & 1;
  const int rsel = lane & 15, quad = lane >> 4;

  f32x4 acc[4][4];
  #pragma unroll
  for (int mi = 0; mi < 4; ++mi)
    #pragma unroll
    for (int ni = 0; ni < 4; ++ni) acc[mi][ni] = (f32x4){0.f, 0.f, 0.f, 0.f};

  #pragma unroll
  for (int ks = 0; ks < 4; ++ks) {
    const int koff = ks * 32 + quad * 8;
    short8 afr[4], bfr[4];
    #pragma unroll
    for (int mi = 0; mi < 4; ++mi) {
      int r = wr * 64 + mi * 16 + rsel;
      afr[mi] = *(const short8*)&Xs[r * 128 + (koff ^ ((r & 7) << 3))];
    }
    #pragma unroll
    for (int ni = 0; ni < 4; ++ni) {
      int r = wc * 64 + ni * 16 + rsel;
      bfr[ni] = *(const short8*)&Ws[r * 128 + (koff ^ ((r & 7) << 3))];
    }
    #pragma unroll
    for (int mi = 0; mi < 4; ++mi)
      #pragma unroll
      for (int ni = 0; ni < 4; ++ni)
        acc[mi][ni] = __builtin_amdgcn_mfma_f32_16x16x32_bf16(afr[mi], bfr[ni], acc[mi][ni], 0, 0, 0);
  }

  unsigned short* dst = (och0 == 0) ? qb : ((och0 == 128) ? kb : vb);
  #pragma unroll
  for (int mi = 0; mi < 4; ++mi)
    #pragma unroll
    for (int ni = 0; ni < 4; ++ni)
      #pragma unroll
      for (int r = 0; r < 4; ++r) {
        int pix = gpix0 + wr * 64 + mi * 16 + quad * 4 + r;
        int ch = wc * 64 + ni * 16 + rsel;
        dst[(size_t)pix * C + ch] = f2bf(acc[mi][ni][r]);
      }
}

// ---------------- Kernel 2: fused gather + attention, scalarized addressing ---
__global__ __launch_bounds__(256) void k_attn(const unsigned short* __restrict__ qb,
                                              const unsigned short* __restrict__ kb,
                                              const unsigned short* __restrict__ vb,
                                              const int* __restrict__ psf,
                                              const float* __restrict__ delta,
                                              unsigned short* __restrict__ ao) {
  const int t = threadIdx.x;
  const int lane = t & 63;
  // wave-uniform pixel id, provably scalar:
  const int spix = __builtin_amdgcn_readfirstlane(blockIdx.x * 4 + (t >> 6));
  const int b = spix >> 14;

  const unsigned* q32 = (const unsigned*)qb;
  const unsigned* k32 = (const unsigned*)kb + (size_t)b * HW * 64;  // SGPR base
  const unsigned* v32 = (const unsigned*)vb + (size_t)b * HW * 64;

  const unsigned qp = q32[(size_t)spix * 64 + lane];
  const float qx = bflo(qp), qy = bfhi(qp);

  // psf anchors: scalar loads
  int anch[16];
  #pragma unroll
  for (int j = 0; j < 16; ++j) anch[j] = psf[(size_t)spix * 16 + j];

  float wgt[8][4];
  int dx0[8], dy0[8];
  #pragma unroll
  for (int k = 0; k < 8; ++k) {
    float s0 = tanhf(delta[k * 2 + 0]) * 4.0f;  // col shift
    float s1 = tanhf(delta[k * 2 + 1]) * 4.0f;  // row shift
    float f0 = floorf(s0), f1 = floorf(s1);
    dx0[k] = __builtin_amdgcn_readfirstlane((int)f0);  // scalar corner offsets
    dy0[k] = __builtin_amdgcn_readfirstlane((int)f1);
    float fx = s0 - f0, fy = s1 - f1;
    wgt[k][0] = (1.0f - fx) * (1.0f - fy);
    wgt[k][1] = fx * (1.0f - fy);
    wgt[k][2] = (1.0f - fx) * fy;
    wgt[k][3] = fx * fy;
  }

  float dk[8];
  float2 vs[8];
  #pragma unroll
  for (int k = 0; k < 8; ++k) {
    const int x0 = anch[k * 2 + 0] + dx0[k], x1 = x0 + 1;   // SALU
    const int y0 = anch[k * 2 + 1] + dy0[k], y1 = y0 + 1;
    float ksx = 0, ksy = 0, vsx = 0, vsy = 0;
    #pragma unroll
    for (int cn = 0; cn < 4; ++cn) {
      const int xi = (cn & 1) ? x1 : x0;                    // SALU
      const int yi = (cn & 2) ? y1 : y0;
      const bool valid = (xi >= 0) & (xi <= 127) & (yi >= 0) & (yi <= 127);
      const int xc = min(max(xi, 0), 127);
      const int yc = min(max(yi, 0), 127);
      const size_t base = (size_t)(yc * 128 + xc) * 64;     // SALU
      const unsigned kk = k32[base + lane];                 // saddr load
      const unsigned vv = v32[base + lane];
      const float wv = valid ? wgt[k][cn] : 0.0f;
      ksx += wv * bflo(kk); ksy += wv * bfhi(kk);
      vsx += wv * bflo(vv); vsy += wv * bfhi(vv);
    }
    vs[k] = make_float2(vsx, vsy);
    dk[k] = qx * ksx + qy * ksy;
  }
  // batched 64-lane butterfly reduction (ILP=8 per level)
  #pragma unroll
  for (int off = 32; off > 0; off >>= 1) {
    #pragma unroll
    for (int k = 0; k < 8; ++k) dk[k] += __shfl_xor(dk[k], off);
  }
  float lg[8];
  float m = dk[0] * 0.08838834764831845f;
  #pragma unroll
  for (int k = 0; k < 8; ++k) { lg[k] = dk[k] * 0.08838834764831845f; m = fmaxf(m, lg[k]); }
  float e[8], den = 0.0f;
  #pragma unroll
  for (int k = 0; k < 8; ++k) { e[k] = __expf(lg[k] - m); den += e[k]; }
  const float inv = 1.0f / den;
  float ox = 0, oy = 0;
  #pragma unroll
  for (int k = 0; k < 8; ++k) { float p = e[k] * inv; ox += p * vs[k].x; oy += p * vs[k].y; }
  ((unsigned*)ao)[(size_t)spix * 64 + lane] = (unsigned)f2bf(ox) | ((unsigned)f2bf(oy) << 16);
}

// ---------------- Kernel 3: out = x + w_proj @ ao  (bf16 MFMA) ----------------
__global__ __launch_bounds__(256) void k_proj(const unsigned short* __restrict__ ao,
                                              const float* __restrict__ w_proj,
                                              const float* __restrict__ x,
                                              float* __restrict__ out) {
  __shared__ __align__(16) unsigned short As[128 * 128];  // [pix][k]
  __shared__ __align__(16) unsigned short Ws[128 * 128];  // [och][k]
  const int t = threadIdx.x;
  const int gpix0 = blockIdx.x * 128;
  const int b = gpix0 >> 14;
  const int hw0 = gpix0 & (HW - 1);

  #pragma unroll
  for (int i = 0; i < 8; ++i) {
    int linear = i * 256 + t;
    int c8 = (linear & 15) * 8;
    int p = linear >> 4;
    uint4 v = *(const uint4*)(ao + (size_t)(gpix0 + p) * C + c8);
    *(uint4*)&As[p * 128 + (c8 ^ ((p & 7) << 3))] = v;
  }
  #pragma unroll
  for (int i = 0; i < 16; ++i) {
    int linear = i * 256 + t;
    int c4 = (linear & 31) * 4;
    int o = linear >> 5;
    float4 w4 = *(const float4*)(w_proj + (size_t)o * C + c4);
    *(unsigned long long*)&Ws[o * 128 + (c4 ^ ((o & 7) << 3))] = pk4(w4.x, w4.y, w4.z, w4.w);
  }
  __syncthreads();

  const int wave = t >> 6, lane = t & 63;
  const int wr = wave >> 1, wc = wave & 1;
  const int rsel = lane & 15, quad = lane >> 4;

  f32x4 acc[4][4];
  #pragma unroll
  for (int mi = 0; mi < 4; ++mi)
    #pragma unroll
    for (int ni = 0; ni < 4; ++ni) acc[mi][ni] = (f32x4){0.f, 0.f, 0.f, 0.f};

  #pragma unroll
  for (int ks = 0; ks < 4; ++ks) {
    const int koff = ks * 32 + quad * 8;
    short8 afr[4], bfr[4];
    #pragma unroll
    for (int mi = 0; mi < 4; ++mi) {
      int r = wr * 64 + mi * 16 + rsel;
      afr[mi] = *(const short8*)&Ws[r * 128 + (koff ^ ((r & 7) << 3))];
    }
    #pragma unroll
    for (int ni = 0; ni < 4; ++ni) {
      int r = wc * 64 + ni * 16 + rsel;
      bfr[ni] = *(const short8*)&As[r * 128 + (koff ^ ((r & 7) << 3))];
    }
    #pragma unroll
    for (int mi = 0; mi < 4; ++mi)
      #pragma unroll
      for (int ni = 0; ni < 4; ++ni)
        acc[mi][ni] = __builtin_amdgcn_mfma_f32_16x16x32_bf16(afr[mi], bfr[ni], acc[mi][ni], 0, 0, 0);
  }

  #pragma unroll
  for (int mi = 0; mi < 4; ++mi)
    #pragma unroll
    for (int ni = 0; ni < 4; ++ni)
      #pragma unroll
      for (int r = 0; r < 4; ++r) {
        int och = wr * 64 + mi * 16 + quad * 4 + r;
        int pixl = wc * 64 + ni * 16 + rsel;
        size_t addr = ((size_t)b * C + och) * HW + hw0 + pixl;
        out[addr] = x[addr] + acc[mi][ni][r];
      }
}

extern "C" void kernel_launch(void* const* d_in, const int* in_sizes, int n_in,
                              void* d_out, int out_size, void* d_ws, size_t ws_size,
                              hipStream_t stream) {
  const float* x      = (const float*)d_in[0];
  const int*   psf    = (const int*)d_in[1];
  const float* delta  = (const float*)d_in[2];
  const float* w_qkv  = (const float*)d_in[3];
  const float* w_proj = (const float*)d_in[4];
  float* out = (float*)d_out;

  const size_t N = (size_t)4 * HW * C;
  unsigned short* qb = (unsigned short*)d_ws;
  unsigned short* kb = qb + N;
  unsigned short* vb = kb + N;
  unsigned short* ao = vb + N;

  k_qkv<<<dim3(512, 3), 256, 0, stream>>>(x, w_qkv, qb, kb, vb);
  k_attn<<<dim3(HW), 256, 0, stream>>>(qb, kb, vb, psf, delta, ao);
  k_proj<<<dim3(512), 256, 0, stream>>>(ao, w_proj, x, out);
}

// Round 5
// 218.481 us; speedup vs baseline: 1.1066x; 1.1066x over previous
//
#include <hip/hip_runtime.h>

#define HW 16384
#define C 128

typedef __attribute__((ext_vector_type(8))) short short8;
typedef __attribute__((ext_vector_type(4))) float f32x4;

__device__ __forceinline__ unsigned short f2bf(float f) {
  union { float f; unsigned u; } v; v.f = f;
  return (unsigned short)((v.u + 0x7fffu + ((v.u >> 16) & 1u)) >> 16);
}
__device__ __forceinline__ float bflo(unsigned w) {
  union { unsigned u; float f; } v; v.u = w << 16; return v.f;
}
__device__ __forceinline__ float bfhi(unsigned w) {
  union { unsigned u; float f; } v; v.u = w & 0xffff0000u; return v.f;
}
__device__ __forceinline__ unsigned long long pk4(float a, float b, float c, float d) {
  return (unsigned long long)f2bf(a) | ((unsigned long long)f2bf(b) << 16) |
         ((unsigned long long)f2bf(c) << 32) | ((unsigned long long)f2bf(d) << 48);
}

// ---------------- Kernel 0: precompute bilinear weights (wave-uniform table) --
// pw[k*4+cn], pi[2k]=dx0, pi[2k+1]=dy0. Kills ~250 uniform VALU ops per k_attn wave.
__global__ void k_prep(const float* __restrict__ delta, float* __restrict__ pw,
                       int* __restrict__ pi) {
  int k = threadIdx.x;
  if (k < 8) {
    float s0 = tanhf(delta[k * 2 + 0]) * 4.0f;  // col shift (x)
    float s1 = tanhf(delta[k * 2 + 1]) * 4.0f;  // row shift (y)
    float f0 = floorf(s0), f1 = floorf(s1);
    pi[2 * k + 0] = (int)f0;
    pi[2 * k + 1] = (int)f1;
    float fx = s0 - f0, fy = s1 - f1;
    pw[4 * k + 0] = (1.0f - fx) * (1.0f - fy);
    pw[4 * k + 1] = fx * (1.0f - fy);
    pw[4 * k + 2] = (1.0f - fx) * fy;
    pw[4 * k + 3] = fx * fy;
  }
}

// ---------------- Kernel 1: qkv = w_qkv @ x  (bf16 MFMA) ----------------------
// q -> qb [pix][ch]; k,v -> interleaved kvb [pix][ch>>1][(k0,k1,v0,v1)] shorts.
__global__ __launch_bounds__(256) void k_qkv(const float* __restrict__ x,
                                             const float* __restrict__ w_qkv,
                                             unsigned short* __restrict__ qb,
                                             unsigned short* __restrict__ kvb) {
  __shared__ __align__(16) unsigned short Xs[128 * 128];
  __shared__ __align__(16) unsigned short Ws[128 * 128];
  const int t = threadIdx.x;
  const int gpix0 = blockIdx.x * 128;
  const int b = gpix0 >> 14;
  const int hw0 = gpix0 & (HW - 1);
  const int och0 = blockIdx.y * 128;

  const float* xb = x + (size_t)b * C * HW + hw0;
  #pragma unroll
  for (int i = 0; i < 16; ++i) {
    int linear = i * 256 + t;
    int p = linear & 127;
    int c4 = (linear >> 7) * 4;
    float a0 = xb[(size_t)(c4 + 0) * HW + p];
    float a1 = xb[(size_t)(c4 + 1) * HW + p];
    float a2 = xb[(size_t)(c4 + 2) * HW + p];
    float a3 = xb[(size_t)(c4 + 3) * HW + p];
    int cc = c4 ^ ((p & 7) << 3);
    *(unsigned long long*)&Xs[p * 128 + cc] = pk4(a0, a1, a2, a3);
  }
  const float* wb = w_qkv + (size_t)och0 * C;
  #pragma unroll
  for (int i = 0; i < 16; ++i) {
    int linear = i * 256 + t;
    int c4 = (linear & 31) * 4;
    int o = linear >> 5;
    float4 w4 = *(const float4*)(wb + (size_t)o * C + c4);
    int cc = c4 ^ ((o & 7) << 3);
    *(unsigned long long*)&Ws[o * 128 + cc] = pk4(w4.x, w4.y, w4.z, w4.w);
  }
  __syncthreads();

  const int wave = t >> 6, lane = t & 63;
  const int wr = wave >> 1, wc = wave & 1;
  const int rsel = lane & 15, quad = lane >> 4;

  f32x4 acc[4][4];
  #pragma unroll
  for (int mi = 0; mi < 4; ++mi)
    #pragma unroll
    for (int ni = 0; ni < 4; ++ni) acc[mi][ni] = (f32x4){0.f, 0.f, 0.f, 0.f};

  #pragma unroll
  for (int ks = 0; ks < 4; ++ks) {
    const int koff = ks * 32 + quad * 8;
    short8 afr[4], bfr[4];
    #pragma unroll
    for (int mi = 0; mi < 4; ++mi) {
      int r = wr * 64 + mi * 16 + rsel;
      afr[mi] = *(const short8*)&Xs[r * 128 + (koff ^ ((r & 7) << 3))];
    }
    #pragma unroll
    for (int ni = 0; ni < 4; ++ni) {
      int r = wc * 64 + ni * 16 + rsel;
      bfr[ni] = *(const short8*)&Ws[r * 128 + (koff ^ ((r & 7) << 3))];
    }
    #pragma unroll
    for (int mi = 0; mi < 4; ++mi)
      #pragma unroll
      for (int ni = 0; ni < 4; ++ni)
        acc[mi][ni] = __builtin_amdgcn_mfma_f32_16x16x32_bf16(afr[mi], bfr[ni], acc[mi][ni], 0, 0, 0);
  }

  if (och0 == 0) {
    #pragma unroll
    for (int mi = 0; mi < 4; ++mi)
      #pragma unroll
      for (int ni = 0; ni < 4; ++ni)
        #pragma unroll
        for (int r = 0; r < 4; ++r) {
          int pix = gpix0 + wr * 64 + mi * 16 + quad * 4 + r;
          int ch = wc * 64 + ni * 16 + rsel;
          qb[(size_t)pix * C + ch] = f2bf(acc[mi][ni][r]);
        }
  } else {
    const int vsel = (och0 == 256) ? 2 : 0;
    #pragma unroll
    for (int mi = 0; mi < 4; ++mi)
      #pragma unroll
      for (int ni = 0; ni < 4; ++ni)
        #pragma unroll
        for (int r = 0; r < 4; ++r) {
          int pix = gpix0 + wr * 64 + mi * 16 + quad * 4 + r;
          int ch = wc * 64 + ni * 16 + rsel;
          kvb[(size_t)pix * 256 + ((ch >> 1) << 2) + (ch & 1) + vsel] = f2bf(acc[mi][ni][r]);
        }
  }
}

// ---------------- Kernel 2: fused gather + attention ---------------------------
// Batch->XCD-pair swizzle; scalar weight table; interleaved kv dwordx2 gathers.
__global__ __launch_bounds__(256) void k_attn(const unsigned short* __restrict__ qb,
                                              const unsigned short* __restrict__ kvb,
                                              const int* __restrict__ psf,
                                              const float* __restrict__ pw,
                                              const int* __restrict__ pi,
                                              unsigned short* __restrict__ ao) {
  const int t = threadIdx.x;
  const int lane = t & 63;
  // swizzle: physical block p -> (batch b, in-batch block j) with p%8 in {2b,2b+1}
  const int p = blockIdx.x;
  const int b = (p >> 1) & 3;
  const int j = ((p >> 3) << 1) | (p & 1);
  const int spix = __builtin_amdgcn_readfirstlane((b << 14) + (j << 2) + (t >> 6));

  const unsigned* q32 = (const unsigned*)qb;
  const unsigned* kv32 = (const unsigned*)kvb + (size_t)b * HW * 128;  // SGPR base

  const unsigned qp = q32[(size_t)spix * 64 + lane];
  const float qx = bflo(qp), qy = bfhi(qp);

  int anch[16];
  #pragma unroll
  for (int jj = 0; jj < 16; ++jj) anch[jj] = psf[(size_t)spix * 16 + jj];

  float dk[8];
  float2 vs[8];
  #pragma unroll
  for (int k = 0; k < 8; ++k) {
    const int x0 = anch[k * 2 + 0] + pi[2 * k + 0], x1 = x0 + 1;  // SALU
    const int y0 = anch[k * 2 + 1] + pi[2 * k + 1], y1 = y0 + 1;
    float ksx = 0, ksy = 0, vsx = 0, vsy = 0;
    #pragma unroll
    for (int cn = 0; cn < 4; ++cn) {
      const int xi = (cn & 1) ? x1 : x0;
      const int yi = (cn & 2) ? y1 : y0;
      const bool valid = (xi >= 0) & (xi <= 127) & (yi >= 0) & (yi <= 127);
      const int xc = min(max(xi, 0), 127);
      const int yc = min(max(yi, 0), 127);
      const float wv = valid ? pw[k * 4 + cn] : 0.0f;                // scalar select
      const size_t base_dw = (size_t)(yc * 128 + xc) * 128;          // SALU
      const uint2 kv2 = *(const uint2*)(kv32 + base_dw + 2 * lane);  // 1 dwordx2
      ksx += wv * bflo(kv2.x); ksy += wv * bfhi(kv2.x);
      vsx += wv * bflo(kv2.y); vsy += wv * bfhi(kv2.y);
    }
    vs[k] = make_float2(vsx, vsy);
    dk[k] = qx * ksx + qy * ksy;
  }
  #pragma unroll
  for (int off = 32; off > 0; off >>= 1) {
    #pragma unroll
    for (int k = 0; k < 8; ++k) dk[k] += __shfl_xor(dk[k], off);
  }
  float lg[8];
  float m = dk[0] * 0.08838834764831845f;
  #pragma unroll
  for (int k = 0; k < 8; ++k) { lg[k] = dk[k] * 0.08838834764831845f; m = fmaxf(m, lg[k]); }
  float e[8], den = 0.0f;
  #pragma unroll
  for (int k = 0; k < 8; ++k) { e[k] = __expf(lg[k] - m); den += e[k]; }
  const float inv = 1.0f / den;
  float ox = 0, oy = 0;
  #pragma unroll
  for (int k = 0; k < 8; ++k) { float pk = e[k] * inv; ox += pk * vs[k].x; oy += pk * vs[k].y; }
  ((unsigned*)ao)[(size_t)spix * 64 + lane] = (unsigned)f2bf(ox) | ((unsigned)f2bf(oy) << 16);
}

// ---------------- Kernel 3: out = x + w_proj @ ao  (bf16 MFMA) ----------------
__global__ __launch_bounds__(256) void k_proj(const unsigned short* __restrict__ ao,
                                              const float* __restrict__ w_proj,
                                              const float* __restrict__ x,
                                              float* __restrict__ out) {
  __shared__ __align__(16) unsigned short As[128 * 128];
  __shared__ __align__(16) unsigned short Ws[128 * 128];
  const int t = threadIdx.x;
  const int gpix0 = blockIdx.x * 128;
  const int b = gpix0 >> 14;
  const int hw0 = gpix0 & (HW - 1);

  #pragma unroll
  for (int i = 0; i < 8; ++i) {
    int linear = i * 256 + t;
    int c8 = (linear & 15) * 8;
    int p = linear >> 4;
    uint4 v = *(const uint4*)(ao + (size_t)(gpix0 + p) * C + c8);
    *(uint4*)&As[p * 128 + (c8 ^ ((p & 7) << 3))] = v;
  }
  #pragma unroll
  for (int i = 0; i < 16; ++i) {
    int linear = i * 256 + t;
    int c4 = (linear & 31) * 4;
    int o = linear >> 5;
    float4 w4 = *(const float4*)(w_proj + (size_t)o * C + c4);
    *(unsigned long long*)&Ws[o * 128 + (c4 ^ ((o & 7) << 3))] = pk4(w4.x, w4.y, w4.z, w4.w);
  }
  __syncthreads();

  const int wave = t >> 6, lane = t & 63;
  const int wr = wave >> 1, wc = wave & 1;
  const int rsel = lane & 15, quad = lane >> 4;

  f32x4 acc[4][4];
  #pragma unroll
  for (int mi = 0; mi < 4; ++mi)
    #pragma unroll
    for (int ni = 0; ni < 4; ++ni) acc[mi][ni] = (f32x4){0.f, 0.f, 0.f, 0.f};

  #pragma unroll
  for (int ks = 0; ks < 4; ++ks) {
    const int koff = ks * 32 + quad * 8;
    short8 afr[4], bfr[4];
    #pragma unroll
    for (int mi = 0; mi < 4; ++mi) {
      int r = wr * 64 + mi * 16 + rsel;
      afr[mi] = *(const short8*)&Ws[r * 128 + (koff ^ ((r & 7) << 3))];
    }
    #pragma unroll
    for (int ni = 0; ni < 4; ++ni) {
      int r = wc * 64 + ni * 16 + rsel;
      bfr[ni] = *(const short8*)&As[r * 128 + (koff ^ ((r & 7) << 3))];
    }
    #pragma unroll
    for (int mi = 0; mi < 4; ++mi)
      #pragma unroll
      for (int ni = 0; ni < 4; ++ni)
        acc[mi][ni] = __builtin_amdgcn_mfma_f32_16x16x32_bf16(afr[mi], bfr[ni], acc[mi][ni], 0, 0, 0);
  }

  #pragma unroll
  for (int mi = 0; mi < 4; ++mi)
    #pragma unroll
    for (int ni = 0; ni < 4; ++ni)
      #pragma unroll
      for (int r = 0; r < 4; ++r) {
        int och = wr * 64 + mi * 16 + quad * 4 + r;
        int pixl = wc * 64 + ni * 16 + rsel;
        size_t addr = ((size_t)b * C + och) * HW + hw0 + pixl;
        out[addr] = x[addr] + acc[mi][ni][r];
      }
}

extern "C" void kernel_launch(void* const* d_in, const int* in_sizes, int n_in,
                              void* d_out, int out_size, void* d_ws, size_t ws_size,
                              hipStream_t stream) {
  const float* x      = (const float*)d_in[0];
  const int*   psf    = (const int*)d_in[1];
  const float* delta  = (const float*)d_in[2];
  const float* w_qkv  = (const float*)d_in[3];
  const float* w_proj = (const float*)d_in[4];
  float* out = (float*)d_out;

  const size_t N = (size_t)4 * HW * C;            // 8388608 elems
  unsigned short* qb  = (unsigned short*)d_ws;    // 16 MB
  unsigned short* kvb = qb + N;                   // 32 MB (k,v interleaved)
  unsigned short* ao  = kvb + 2 * N;              // 16 MB
  float* pw = (float*)(ao + N);                   // 32 floats
  int*   pi = (int*)(pw + 32);                    // 16 ints

  k_prep<<<1, 64, 0, stream>>>(delta, pw, pi);
  k_qkv<<<dim3(512, 3), 256, 0, stream>>>(x, w_qkv, qb, kvb);
  k_attn<<<dim3(HW), 256, 0, stream>>>(qb, kvb, psf, pw, pi, ao);
  k_proj<<<dim3(512), 256, 0, stream>>>(ao, w_proj, x, out);
}